// Round 7
// baseline (8053.495 us; speedup 1.0000x reference)
//
#include <hip/hip_runtime.h>

// MI-LSTM on MI355X (gfx950). FP32 I/O, bf16 MFMA compute, fp32 accumulate.
// B=128, T=256, D_IN=1024, UNITS=1024, N_CLASS=1024.
//
// R6: persistent chunk kernel. One launch per 32-step chunk; 256 blocks stay
// resident, WrT slice (32 KB) LDS-resident across the chunk, c slice in
// registers, device-scope atomic grid barrier + agent fences between steps.
// Replaces 256 per-step launches (≈10 us launch overhead each) with 8.

typedef unsigned short u16;
typedef __attribute__((ext_vector_type(8))) short short8;   // 8 x bf16
typedef __attribute__((ext_vector_type(4))) float f32x4;    // MFMA accumulator

#define B_SZ   128
#define T_SZ   256
#define D_IN   1024
#define UNITS  1024
#define FOURU  4096

__device__ __forceinline__ float bf2f(u16 h) {
    return __uint_as_float(((unsigned int)h) << 16);
}
__device__ __forceinline__ u16 f2bf(float f) {
    unsigned int u = __float_as_uint(f);
    u += 0x7fffu + ((u >> 16) & 1u);   // round-to-nearest-even
    return (u16)(u >> 16);
}
__device__ __forceinline__ float sigmoidf_(float x) {
    return 1.0f / (1.0f + __expf(-x));
}

// ---------------------------------------------------------------- transpose+cvt
__global__ __launch_bounds__(256) void transpose_cvt(
    const float* __restrict__ in, u16* __restrict__ out, int K, int N)
{
    __shared__ u16 t[32][33];
    int n0 = blockIdx.x * 32, k0 = blockIdx.y * 32;
    int c = threadIdx.x & 31, r = threadIdx.x >> 5;
    #pragma unroll
    for (int i = 0; i < 4; ++i) {
        int kk = r + i * 8;
        t[kk][c] = f2bf(in[(size_t)(k0 + kk) * N + n0 + c]);
    }
    __syncthreads();
    #pragma unroll
    for (int i = 0; i < 4; ++i) {
        int nn = r + i * 8;
        out[(size_t)(n0 + nn) * K + k0 + c] = t[c][nn];
    }
}

// ---------------------------------------------------------------- XP GEMM (one time-chunk)
__global__ __launch_bounds__(256) void gemm_xp_chunk(
    const float* __restrict__ X, const u16* __restrict__ Bt,
    const float* __restrict__ bias, u16* __restrict__ Cc,
    int t0, int tcShift)
{
    __shared__ __align__(16) u16 As[128 * 40];
    __shared__ __align__(16) u16 Bs[128 * 40];
    int tid = threadIdx.x;
    int wave = tid >> 6, lane = tid & 63;
    int bm = blockIdx.x * 128;
    int bn = blockIdx.y * 128;
    int wm = (wave & 1) * 64, wn = (wave >> 1) * 64;
    int lm = lane & 15, lq = lane >> 4;
    int tcMask = (1 << tcShift) - 1;

    f32x4 acc[4][4] = {};

    for (int k0 = 0; k0 < D_IN; k0 += 32) {
        #pragma unroll
        for (int i = 0; i < 2; ++i) {
            int idx = tid + i * 256;
            int r = idx >> 2, q = idx & 3;
            int rowp = bm + r;
            int b = rowp >> tcShift;
            int tt = rowp & tcMask;
            const float* xs = &X[(size_t)(b * T_SZ + t0 + tt) * D_IN + k0 + q * 8];
            float4 f0 = *(const float4*)xs;
            float4 f1 = *(const float4*)(xs + 4);
            uint4 v;
            v.x = (unsigned)f2bf(f0.x) | ((unsigned)f2bf(f0.y) << 16);
            v.y = (unsigned)f2bf(f0.z) | ((unsigned)f2bf(f0.w) << 16);
            v.z = (unsigned)f2bf(f1.x) | ((unsigned)f2bf(f1.y) << 16);
            v.w = (unsigned)f2bf(f1.z) | ((unsigned)f2bf(f1.w) << 16);
            *(uint4*)&As[r * 40 + q * 8] = v;
            *(uint4*)&Bs[r * 40 + q * 8] =
                *(const uint4*)&Bt[(size_t)(bn + r) * D_IN + k0 + q * 8];
        }
        __syncthreads();
        short8 af[4], bf[4];
        #pragma unroll
        for (int t = 0; t < 4; ++t) {
            af[t] = *(const short8*)&As[(wm + t * 16 + lm) * 40 + lq * 8];
            bf[t] = *(const short8*)&Bs[(wn + t * 16 + lm) * 40 + lq * 8];
        }
        #pragma unroll
        for (int mt = 0; mt < 4; ++mt)
            #pragma unroll
            for (int nt = 0; nt < 4; ++nt)
                acc[mt][nt] = __builtin_amdgcn_mfma_f32_16x16x32_bf16(
                    af[mt], bf[nt], acc[mt][nt], 0, 0, 0);
        __syncthreads();
    }

    #pragma unroll
    for (int mt = 0; mt < 4; ++mt) {
        #pragma unroll
        for (int nt = 0; nt < 4; ++nt) {
            int col = bn + wn + nt * 16 + lm;
            float bv = bias[col];
            #pragma unroll
            for (int r = 0; r < 4; ++r) {
                int rowp = bm + wm + mt * 16 + lq * 4 + r;
                Cc[(size_t)rowp * FOURU + col] = f2bf(acc[mt][nt][r] + bv);
            }
        }
    }
}

// ---------------------------------------------------------------- grid barrier
__device__ __forceinline__ void grid_sync(unsigned* bar, unsigned nb) {
    // bar[0] = arrival count, bar[1] = generation
    __syncthreads();
    if (threadIdx.x == 0) {
        __builtin_amdgcn_fence(__ATOMIC_RELEASE, "agent");
        unsigned g = __hip_atomic_load(&bar[1], __ATOMIC_RELAXED, __HIP_MEMORY_SCOPE_AGENT);
        unsigned v = __hip_atomic_fetch_add(&bar[0], 1u, __ATOMIC_RELAXED, __HIP_MEMORY_SCOPE_AGENT);
        if (v == nb - 1) {
            __hip_atomic_store(&bar[0], 0u, __ATOMIC_RELAXED, __HIP_MEMORY_SCOPE_AGENT);
            __hip_atomic_fetch_add(&bar[1], 1u, __ATOMIC_RELEASE, __HIP_MEMORY_SCOPE_AGENT);
        } else {
            while (__hip_atomic_load(&bar[1], __ATOMIC_RELAXED, __HIP_MEMORY_SCOPE_AGENT) == g)
                __builtin_amdgcn_s_sleep(1);
        }
        __builtin_amdgcn_fence(__ATOMIC_ACQUIRE, "agent");
    }
    __syncthreads();
}

// ---------------------------------------------------------------- persistent chunk
// 256 blocks x 256 threads, all co-resident. Block owns u0=blockIdx*4:
// 4 u-cols x 4 gates = 16 n-cols. WrT slice (16x1024 bf16) in LDS for the
// whole chunk; c slice (128 rows x 4 cols -> 2/thread) in registers.
// Per step: hp = h @ WrS (h read global, L2-hot), fused MI gates, write h
// slice, grid barrier (skipped on last step: kernel boundary syncs).
__global__ __launch_bounds__(256) void milstm_chunk(
    const u16* __restrict__ XPc,     // bf16 [B*tc][4096], row' = b*tc+tt
    const u16* __restrict__ WrT,     // [4096][1024] bf16
    const float* __restrict__ br,
    const float* __restrict__ alpha,
    const float* __restrict__ beta1,
    const float* __restrict__ beta2,
    u16* __restrict__ hb0,           // ping-pong h (bf16 [128][1024])
    u16* __restrict__ hb1,
    float* __restrict__ cbuf,        // fp32 [128][1024]
    unsigned* __restrict__ bar,
    int t0, int tc)
{
    __shared__ __align__(16) u16 WrS[16 * 1032];
    __shared__ float zbuf[16][132];
    __shared__ float brS[16], alS[16], b1S[16], b2S[16];

    int tid = threadIdx.x;
    int wave = tid >> 6, lane = tid & 63;
    int lm = lane & 15, lq = lane >> 4;
    int u0 = blockIdx.x * 4;

    // stage WrT slice (once per chunk): 16 rows x 1024 bf16 = 2048 uint4
    #pragma unroll
    for (int i = 0; i < 8; ++i) {
        int idx = i * 256 + tid;
        int l = idx >> 7, q = idx & 127;
        int n = ((l >> 2) << 10) + u0 + (l & 3);
        *(uint4*)&WrS[l * 1032 + q * 8] = *(const uint4*)&WrT[(size_t)n * 1024 + q * 8];
    }
    if (tid < 16) {
        int n = ((tid >> 2) << 10) + u0 + (tid & 3);
        brS[tid] = br[n]; alS[tid] = alpha[n];
        b1S[tid] = beta1[n]; b2S[tid] = beta2[n];
    }

    // c slice in registers: thread owns (row=tid>>2, j=tid&3) and (row+64, j)
    int jc = tid & 3, rowA = tid >> 2, rowB = rowA + 64;
    float cA = cbuf[(size_t)rowA * UNITS + u0 + jc];
    float cB = cbuf[(size_t)rowB * UNITS + u0 + jc];
    __syncthreads();

    for (int tt = 0; tt < tc; ++tt) {
        int t = t0 + tt;
        const u16* hin = (t & 1) ? hb1 : hb0;
        u16* hout = (t & 1) ? hb0 : hb1;

        // hp = h @ WrS : wave handles m-tiles {wave, wave+4}
        const u16* A0 = &hin[(size_t)(wave * 16 + lm) * UNITS];
        const u16* A1 = &hin[(size_t)((wave + 4) * 16 + lm) * UNITS];
        const u16* Bl = &WrS[lm * 1032];
        f32x4 acc0 = {}, acc1 = {};
        #pragma unroll 8
        for (int k0 = 0; k0 < UNITS; k0 += 32) {
            short8 b  = *(const short8*)&Bl[k0 + lq * 8];
            short8 a0 = *(const short8*)&A0[k0 + lq * 8];
            short8 a1 = *(const short8*)&A1[k0 + lq * 8];
            acc0 = __builtin_amdgcn_mfma_f32_16x16x32_bf16(a0, b, acc0, 0, 0, 0);
            acc1 = __builtin_amdgcn_mfma_f32_16x16x32_bf16(a1, b, acc1, 0, 0, 0);
        }
        #pragma unroll
        for (int r = 0; r < 4; ++r) {
            zbuf[lm][wave * 16 + lq * 4 + r]       = acc0[r];
            zbuf[lm][(wave + 4) * 16 + lq * 4 + r] = acc1[r];
        }
        __syncthreads();

        // fused MI gates: 512 items = 128 rows x 4 u-cols (2 per thread)
        #pragma unroll
        for (int e = 0; e < 2; ++e) {
            int row = e ? rowB : rowA;
            float z[4];
            #pragma unroll
            for (int g = 0; g < 4; ++g) {
                int l = g * 4 + jc;
                float hp = zbuf[l][row] + brS[l];
                float xp = bf2f(XPc[(size_t)row * (tc * FOURU) + (size_t)tt * FOURU
                                    + ((g << 10) + u0 + jc)]);
                z[g] = alS[l] * xp * hp + b1S[l] * xp + b2S[l] * hp;
            }
            float c = e ? cB : cA;
            float cn = tanhf(z[2]) * sigmoidf_(z[0]) + c * sigmoidf_(z[1]);
            if (e) cB = cn; else cA = cn;
            hout[(size_t)row * UNITS + u0 + jc] = f2bf(tanhf(cn) * sigmoidf_(z[3]));
        }

        if (tt != tc - 1) grid_sync(bar, gridDim.x);
    }

    // write back c slice
    cbuf[(size_t)rowA * UNITS + u0 + jc] = cA;
    cbuf[(size_t)rowB * UNITS + u0 + jc] = cB;
}

// ---------------------------------------------------------------- final GEMM
__global__ __launch_bounds__(256) void gemm_out(
    const u16* __restrict__ h, const u16* __restrict__ WcT,
    const float* __restrict__ bc, float* __restrict__ out)
{
    int tid = threadIdx.x;
    int wave = tid >> 6, lane = tid & 63;
    int bx = blockIdx.x;
    int row0 = (bx & 7) * 16;
    int n0 = (bx >> 3) * 64 + wave * 16;
    int lm = lane & 15, lq = lane >> 4;

    f32x4 acc = {};
    const u16* Arow = &h[(size_t)(row0 + lm) * UNITS];
    const u16* Brow = &WcT[(size_t)(n0 + lm) * UNITS];
    #pragma unroll 8
    for (int k0 = 0; k0 < UNITS; k0 += 32) {
        short8 a = *(const short8*)&Arow[k0 + lq * 8];
        short8 b = *(const short8*)&Brow[k0 + lq * 8];
        acc = __builtin_amdgcn_mfma_f32_16x16x32_bf16(a, b, acc, 0, 0, 0);
    }
    int col = n0 + lm;
    float bv = bc[col];
    #pragma unroll
    for (int r = 0; r < 4; ++r) {
        int row = row0 + lq * 4 + r;
        out[(size_t)row * 1024 + col] = acc[r] + bv;
    }
}

// ---------------------------------------------------------------- utilities
__global__ void cvt_f32_bf16(const float* __restrict__ in, u16* __restrict__ out, int n) {
    int i = blockIdx.x * 256 + threadIdx.x;
    if (i < n) out[i] = f2bf(in[i]);
}
__global__ void cvt_bf16_f32(const u16* __restrict__ in, float* __restrict__ out, int n) {
    int i = blockIdx.x * 256 + threadIdx.x;
    if (i < n) out[i] = bf2f(in[i]);
}
__global__ void copy_f32(const float* __restrict__ in, float* __restrict__ out, int n) {
    int i = blockIdx.x * 256 + threadIdx.x;
    if (i < n) out[i] = in[i];
}
__global__ void zero_u32(unsigned* __restrict__ p, int n) {
    int i = blockIdx.x * 256 + threadIdx.x;
    if (i < n) p[i] = 0u;
}

// ---------------------------------------------------------------- launch
extern "C" void kernel_launch(void* const* d_in, const int* in_sizes, int n_in,
                              void* d_out, int out_size, void* d_ws, size_t ws_size,
                              hipStream_t stream)
{
    const float* x     = (const float*)d_in[0];
    const float* h0    = (const float*)d_in[1];
    const float* c0    = (const float*)d_in[2];
    const float* Wk    = (const float*)d_in[3];
    const float* bk    = (const float*)d_in[4];
    const float* Wr    = (const float*)d_in[5];
    const float* br    = (const float*)d_in[6];
    const float* alpha = (const float*)d_in[7];
    const float* beta1 = (const float*)d_in[8];
    const float* beta2 = (const float*)d_in[9];
    const float* Wc    = (const float*)d_in[10];
    const float* bc    = (const float*)d_in[11];
    float* out = (float*)d_out;

    char* p = (char*)d_ws;
    unsigned* bar = (unsigned*)p; p += 256;                      // barrier line
    u16* hb0  = (u16*)p;  p += (size_t)B_SZ * UNITS * 2;
    u16* hb1  = (u16*)p;  p += (size_t)B_SZ * UNITS * 2;
    float* cbuf = (float*)p; p += (size_t)B_SZ * UNITS * 4;
    u16* WkT = (u16*)p;   p += (size_t)FOURU * D_IN * 2;
    u16* WrT = (u16*)p;   p += (size_t)FOURU * UNITS * 2;
    u16* WcT = (u16*)p;   p += (size_t)1024 * 1024 * 2;
    u16* XPc = (u16*)p;   // bf16 [B_SZ*tc][4096]

    size_t fixedB = (size_t)(p - (char*)d_ws);
    int tc = 32, tcShift = 5;
    while (tc > 1 && fixedB + (size_t)B_SZ * tc * FOURU * 2 > ws_size) {
        tc >>= 1; tcShift -= 1;
    }

    zero_u32<<<1, 256, 0, stream>>>(bar, 2);

    transpose_cvt<<<dim3(FOURU / 32, D_IN / 32), 256, 0, stream>>>(Wk, WkT, D_IN, FOURU);
    transpose_cvt<<<dim3(FOURU / 32, UNITS / 32), 256, 0, stream>>>(Wr, WrT, UNITS, FOURU);
    transpose_cvt<<<dim3(1024 / 32, 1024 / 32), 256, 0, stream>>>(Wc, WcT, 1024, 1024);

    // state init: h0 -> bf16 in hb0 (t=0 reads hb0), c0 -> fp32 scratch
    cvt_f32_bf16<<<(B_SZ * UNITS) / 256, 256, 0, stream>>>(h0, hb0, B_SZ * UNITS);
    copy_f32<<<(B_SZ * UNITS) / 256, 256, 0, stream>>>(c0, cbuf, B_SZ * UNITS);

    // recurrence: per chunk, XP GEMM then persistent 32-step kernel
    for (int t0 = 0; t0 < T_SZ; t0 += tc) {
        gemm_xp_chunk<<<dim3(tc, FOURU / 128), 256, 0, stream>>>(
            x, WkT, bk, XPc, t0, tcShift);
        milstm_chunk<<<256, 256, 0, stream>>>(
            XPc, WrT, br, alpha, beta1, beta2,
            hb0, hb1, cbuf, bar, t0, tc);
    }
    // t=255 (odd): hin=hb1, hout=hb0  =>  final h is in hb0.
    u16* hfin = (T_SZ & 1) ? hb1 : hb0;

    gemm_out<<<128, 256, 0, stream>>>(hfin, WcT, bc, out);
    cvt_bf16_f32<<<(B_SZ * UNITS) / 256, 256, 0, stream>>>(hfin, out + B_SZ * UNITS, B_SZ * UNITS);
    copy_f32<<<(B_SZ * UNITS) / 256, 256, 0, stream>>>(cbuf, out + 2 * B_SZ * UNITS, B_SZ * UNITS);
}